// Round 1
// baseline (263.666 us; speedup 1.0000x reference)
//
#include <hip/hip_runtime.h>

#define BB 8
#define NN 512
#define SS 96
#define HH 256
#define NHD 8
#define HDD 32
#define OUTD 4

// ws layout (floats)
#define Q_OFF   0
#define K_OFF   (4096*256)                 // 1048576
#define V_OFF   (K_OFF + 768*256)          // 1245184
#define CTX_OFF (V_OFF + 768*256)          // 1441792

// ---------------- Kernel 1: temporal -> tp -> (k, v) ----------------
// grid 96 blocks x 256 threads, 8 rows/block
__global__ __launch_bounds__(256) void k_temporal(
    const float* __restrict__ temporal,
    const float* __restrict__ Wt, const float* __restrict__ bt,
    const float* __restrict__ Win, const float* __restrict__ bin,
    float* __restrict__ k_out, float* __restrict__ v_out)
{
    __shared__ __align__(16) float tin[8][HH];
    __shared__ __align__(16) float tp[8][HH];
    const int tid = threadIdx.x;
    const int r0 = blockIdx.x * 8;   // row = b*S+s

    const float4* g4 = (const float4*)(temporal + (size_t)r0 * HH);
    float4* t4 = (float4*)&tin[0][0];
    for (int i = tid; i < 8 * HH / 4; i += 256) t4[i] = g4[i];
    __syncthreads();

    const int j = tid;
    {
        float acc[8] = {};
        const float4* w4 = (const float4*)(Wt + (size_t)j * HH);
        for (int kk = 0; kk < HH / 4; ++kk) {
            float4 w = w4[kk];
            #pragma unroll
            for (int r = 0; r < 8; ++r) {
                float4 a = ((const float4*)tin[r])[kk];
                acc[r] += a.x * w.x + a.y * w.y + a.z * w.z + a.w * w.w;
            }
        }
        float bb = bt[j];
        #pragma unroll
        for (int r = 0; r < 8; ++r) tp[r][j] = acc[r] + bb;
    }
    __syncthreads();
    {
        float ka[8] = {}, va[8] = {};
        const float4* wk4 = (const float4*)(Win + (size_t)(HH + j) * HH);
        const float4* wv4 = (const float4*)(Win + (size_t)(2 * HH + j) * HH);
        for (int kk = 0; kk < HH / 4; ++kk) {
            float4 wk = wk4[kk], wv = wv4[kk];
            #pragma unroll
            for (int r = 0; r < 8; ++r) {
                float4 a = ((const float4*)tp[r])[kk];
                ka[r] += a.x * wk.x + a.y * wk.y + a.z * wk.z + a.w * wk.w;
                va[r] += a.x * wv.x + a.y * wv.y + a.z * wv.z + a.w * wv.w;
            }
        }
        float bk = bin[HH + j], bv = bin[2 * HH + j];
        #pragma unroll
        for (int r = 0; r < 8; ++r) {
            k_out[(size_t)(r0 + r) * HH + j] = ka[r] + bk;
            v_out[(size_t)(r0 + r) * HH + j] = va[r] + bv;
        }
    }
}

// ---------------- Kernel 2: spatial -> sp -> q ----------------
// grid 256 blocks x 256 threads, 16 rows/block
__global__ __launch_bounds__(256) void k_spatial(
    const float* __restrict__ spatial,
    const float* __restrict__ Ws, const float* __restrict__ bs,
    const float* __restrict__ Win, const float* __restrict__ bin,
    float* __restrict__ q_out)
{
    __shared__ __align__(16) float sin_[16][HH];
    __shared__ __align__(16) float sp[16][HH];
    const int tid = threadIdx.x;
    const int r0 = blockIdx.x * 16;   // row = b*N+n

    const float4* g4 = (const float4*)(spatial + (size_t)r0 * HH);
    float4* t4 = (float4*)&sin_[0][0];
    for (int i = tid; i < 16 * HH / 4; i += 256) t4[i] = g4[i];
    __syncthreads();

    const int j = tid;
    {
        float acc[16] = {};
        const float4* w4 = (const float4*)(Ws + (size_t)j * HH);
        for (int kk = 0; kk < HH / 4; ++kk) {
            float4 w = w4[kk];
            #pragma unroll
            for (int r = 0; r < 16; ++r) {
                float4 a = ((const float4*)sin_[r])[kk];
                acc[r] += a.x * w.x + a.y * w.y + a.z * w.z + a.w * w.w;
            }
        }
        float bb = bs[j];
        #pragma unroll
        for (int r = 0; r < 16; ++r) sp[r][j] = acc[r] + bb;
    }
    __syncthreads();
    {
        float acc[16] = {};
        const float4* w4 = (const float4*)(Win + (size_t)j * HH);  // Wq rows
        for (int kk = 0; kk < HH / 4; ++kk) {
            float4 w = w4[kk];
            #pragma unroll
            for (int r = 0; r < 16; ++r) {
                float4 a = ((const float4*)sp[r])[kk];
                acc[r] += a.x * w.x + a.y * w.y + a.z * w.z + a.w * w.w;
            }
        }
        float bb = bin[j];
        #pragma unroll
        for (int r = 0; r < 16; ++r)
            q_out[(size_t)(r0 + r) * HH + j] = acc[r] + bb;
    }
}

// ---------------- Kernel 3: attention ----------------
// grid B*NH*2 = 128 blocks x 256 threads; each thread owns one n-row
__global__ __launch_bounds__(256) void k_attn(
    const float* __restrict__ qg, const float* __restrict__ kg,
    const float* __restrict__ vg, float* __restrict__ ctxg)
{
    __shared__ __align__(16) float kl[SS][HDD];
    __shared__ __align__(16) float vl[SS][HDD];
    const int tid = threadIdx.x;
    const int blk = blockIdx.x;
    const int c = blk & 1;
    const int h = (blk >> 1) & (NHD - 1);
    const int b = blk >> 4;

    for (int i = tid; i < SS * HDD / 4; i += 256) {
        int s = i >> 3, d4 = i & 7;
        ((float4*)kl[s])[d4] = *(const float4*)(kg + (size_t)(b * SS + s) * HH + h * HDD + d4 * 4);
        ((float4*)vl[s])[d4] = *(const float4*)(vg + (size_t)(b * SS + s) * HH + h * HDD + d4 * 4);
    }
    __syncthreads();

    const int n = c * 256 + tid;
    const float4* q4 = (const float4*)(qg + (size_t)(b * NN + n) * HH + h * HDD);
    float4 q[8];
    #pragma unroll
    for (int i = 0; i < 8; ++i) q[i] = q4[i];

    const float scale = 0.17677669529663687f;  // 1/sqrt(32)
    float m = -1e30f;
    for (int s = 0; s < SS; ++s) {
        float dot = 0.f;
        #pragma unroll
        for (int i = 0; i < 8; ++i) {
            float4 kk = ((const float4*)kl[s])[i];
            dot += q[i].x * kk.x + q[i].y * kk.y + q[i].z * kk.z + q[i].w * kk.w;
        }
        m = fmaxf(m, dot * scale);
    }
    float sum = 0.f;
    float ctx[HDD] = {};
    for (int s = 0; s < SS; ++s) {
        float dot = 0.f;
        #pragma unroll
        for (int i = 0; i < 8; ++i) {
            float4 kk = ((const float4*)kl[s])[i];
            dot += q[i].x * kk.x + q[i].y * kk.y + q[i].z * kk.z + q[i].w * kk.w;
        }
        float p = __expf(dot * scale - m);
        sum += p;
        #pragma unroll
        for (int i = 0; i < 8; ++i) {
            float4 vv = ((const float4*)vl[s])[i];
            ctx[i * 4 + 0] += p * vv.x;
            ctx[i * 4 + 1] += p * vv.y;
            ctx[i * 4 + 2] += p * vv.z;
            ctx[i * 4 + 3] += p * vv.w;
        }
    }
    float inv = 1.0f / sum;
    float4* o4 = (float4*)(ctxg + (size_t)(b * NN + n) * HH + h * HDD);
    #pragma unroll
    for (int i = 0; i < 8; ++i)
        o4[i] = make_float4(ctx[i * 4 + 0] * inv, ctx[i * 4 + 1] * inv,
                            ctx[i * 4 + 2] * inv, ctx[i * 4 + 3] * inv);
}

// ---------------- Kernel 4: ctx -> attended -> fused -> h2 -> y -> broadcast ----------------
// grid 256 blocks x 256 threads, 16 rows/block
__global__ __launch_bounds__(256) void k_head(
    const float* __restrict__ ctxg,
    const float* __restrict__ Wao, const float* __restrict__ bao,
    const float* __restrict__ W1, const float* __restrict__ b1,
    const float* __restrict__ Wo1, const float* __restrict__ bo1,
    const float* __restrict__ Wo2, const float* __restrict__ bo2,
    float* __restrict__ out)
{
    __shared__ __align__(16) float A[16][HH];
    __shared__ __align__(16) float Bf[16][HH];
    __shared__ __align__(16) float y[16][OUTD];
    const int tid = threadIdx.x;
    const int r0 = blockIdx.x * 16;  // row = b*N+n

    const float4* g4 = (const float4*)(ctxg + (size_t)r0 * HH);
    float4* a4 = (float4*)&A[0][0];
    for (int i = tid; i < 16 * HH / 4; i += 256) a4[i] = g4[i];
    __syncthreads();

    const int j = tid;
    // attended = ctx @ Wao.T + bao  -> Bf
    {
        float acc[16] = {};
        const float4* w4 = (const float4*)(Wao + (size_t)j * HH);
        for (int kk = 0; kk < HH / 4; ++kk) {
            float4 w = w4[kk];
            #pragma unroll
            for (int r = 0; r < 16; ++r) {
                float4 a = ((const float4*)A[r])[kk];
                acc[r] += a.x * w.x + a.y * w.y + a.z * w.z + a.w * w.w;
            }
        }
        float bb = bao[j];
        #pragma unroll
        for (int r = 0; r < 16; ++r) Bf[r][j] = acc[r] + bb;
    }
    __syncthreads();
    // fused = relu(attended @ W1.T + b1) -> A
    {
        float acc[16] = {};
        const float4* w4 = (const float4*)(W1 + (size_t)j * HH);
        for (int kk = 0; kk < HH / 4; ++kk) {
            float4 w = w4[kk];
            #pragma unroll
            for (int r = 0; r < 16; ++r) {
                float4 a = ((const float4*)Bf[r])[kk];
                acc[r] += a.x * w.x + a.y * w.y + a.z * w.z + a.w * w.w;
            }
        }
        float bb = b1[j];
        #pragma unroll
        for (int r = 0; r < 16; ++r) A[r][j] = fmaxf(acc[r] + bb, 0.f);
    }
    __syncthreads();
    // h2 = relu(fused @ Wo1.T + bo1) -> Bf[.][0..127]
    {
        const int jj = tid & 127;
        const int rh = tid >> 7;  // 0/1: rows rh*8 .. rh*8+7
        float acc[8] = {};
        const float4* w4 = (const float4*)(Wo1 + (size_t)jj * HH);
        for (int kk = 0; kk < HH / 4; ++kk) {
            float4 w = w4[kk];
            #pragma unroll
            for (int r = 0; r < 8; ++r) {
                float4 a = ((const float4*)A[rh * 8 + r])[kk];
                acc[r] += a.x * w.x + a.y * w.y + a.z * w.z + a.w * w.w;
            }
        }
        float bb = bo1[jj];
        #pragma unroll
        for (int r = 0; r < 8; ++r) Bf[rh * 8 + r][jj] = fmaxf(acc[r] + bb, 0.f);
    }
    __syncthreads();
    // y = h2 @ Wo2.T + bo2 (dots of 128)
    if (tid < 64) {
        int r = tid >> 2, o = tid & 3;
        float acc = 0.f;
        const float4* w4 = (const float4*)(Wo2 + (size_t)o * (HH / 2));
        for (int kk = 0; kk < (HH / 2) / 4; ++kk) {
            float4 w = w4[kk];
            float4 a = ((const float4*)Bf[r])[kk];
            acc += a.x * w.x + a.y * w.y + a.z * w.z + a.w * w.w;
        }
        y[r][o] = acc + bo2[o];
    }
    __syncthreads();
    // broadcast: out[b][s][n][o] = y[n-row]; 16 rows x 96 s
    const int b = r0 >> 9;
    const int nbase = r0 & 511;
    for (int i = tid; i < 16 * SS; i += 256) {
        int s = i >> 4;
        int r = i & 15;
        float4 val = *(const float4*)y[r];
        *(float4*)(out + ((size_t)(b * SS + s) * NN + (nbase + r)) * OUTD) = val;
    }
}

extern "C" void kernel_launch(void* const* d_in, const int* in_sizes, int n_in,
                              void* d_out, int out_size, void* d_ws, size_t ws_size,
                              hipStream_t stream) {
    const float* spatial  = (const float*)d_in[0];
    const float* temporal = (const float*)d_in[1];
    const float* Ws  = (const float*)d_in[2];
    const float* bs  = (const float*)d_in[3];
    const float* Wt  = (const float*)d_in[4];
    const float* bt  = (const float*)d_in[5];
    const float* Win = (const float*)d_in[6];
    const float* bin = (const float*)d_in[7];
    const float* Wao = (const float*)d_in[8];
    const float* bao = (const float*)d_in[9];
    const float* W1  = (const float*)d_in[10];
    const float* b1  = (const float*)d_in[11];
    const float* Wo1 = (const float*)d_in[12];
    const float* bo1 = (const float*)d_in[13];
    const float* Wo2 = (const float*)d_in[14];
    const float* bo2 = (const float*)d_in[15];
    float* out = (float*)d_out;
    float* ws  = (float*)d_ws;

    float* qbuf   = ws + Q_OFF;
    float* kbuf   = ws + K_OFF;
    float* vbuf   = ws + V_OFF;
    float* ctxbuf = ws + CTX_OFF;

    hipLaunchKernelGGL(k_temporal, dim3(BB * SS / 8), dim3(256), 0, stream,
                       temporal, Wt, bt, Win, bin, kbuf, vbuf);
    hipLaunchKernelGGL(k_spatial, dim3(BB * NN / 16), dim3(256), 0, stream,
                       spatial, Ws, bs, Win, bin, qbuf);
    hipLaunchKernelGGL(k_attn, dim3(BB * NHD * 2), dim3(256), 0, stream,
                       qbuf, kbuf, vbuf, ctxbuf);
    hipLaunchKernelGGL(k_head, dim3(BB * NN / 16), dim3(256), 0, stream,
                       ctxbuf, Wao, bao, W1, b1, Wo1, bo1, Wo2, bo2, out);
}